// Round 1
// baseline (2641.834 us; speedup 1.0000x reference)
//
#include <hip/hip_runtime.h>
#include <hip/hip_bf16.h>
#include <math.h>

#define BB 256      // batch
#define TT 96       // seq len
#define PP 96       // pred len
#define CC 321      // enc_in
#define CP 352      // padded enc_in (11*32)
#define DD 512      // d_model
#define GG 2048     // 4*DD

typedef __attribute__((ext_vector_type(8))) short bf16x8;
typedef __attribute__((ext_vector_type(4))) float f32x4;
typedef __hip_bfloat16 bf16;

// ---------------------------------------------------------------------------
// Instance norm over time: mean/stdev per (b,c); write normalized x to
// xnorm[t][b][c] (bf16, row pitch CP, pad cols pre-zeroed by memset).
__global__ void norm_kernel(const float* __restrict__ x, float* __restrict__ meanp,
                            float* __restrict__ stdp, bf16* __restrict__ xn) {
    int g = blockIdx.x * 256 + threadIdx.x;      // 0 .. BB*CC-1
    if (g >= BB * CC) return;
    int b = g / CC, c = g % CC;
    const float* xp = x + b * TT * CC + c;
    float s = 0.f;
    for (int t = 0; t < TT; ++t) s += xp[t * CC];
    float mu = s * (1.f / TT);
    float v = 0.f;
    for (int t = 0; t < TT; ++t) { float d0 = xp[t * CC] - mu; v += d0 * d0; }
    float sd = sqrtf(v * (1.f / TT) + 1e-5f);
    float rs = 1.f / sd;
    meanp[g] = mu;
    stdp[g] = sd;
    for (int t = 0; t < TT; ++t)
        xn[(t * BB + b) * CP + c] = __float2bfloat16((xp[t * CC] - mu) * rs);
}

// Cast fp32 [rows][cols] -> bf16 [rows][ldd] (pad cols pre-zeroed if ldd>cols)
__global__ void cast_pad_kernel(const float* __restrict__ src, bf16* __restrict__ dst,
                                int rows, int cols, int ldd) {
    int i = blockIdx.x * 256 + threadIdx.x;
    if (i >= rows * cols) return;
    int r = i / cols, c = i % cols;
    dst[r * ldd + c] = __float2bfloat16(src[i]);
}

// WpT[d][c] = Wp[c][d]  (bf16, row pitch CP, pad pre-zeroed)
__global__ void transpose_wp_kernel(const float* __restrict__ wp, bf16* __restrict__ wpt) {
    int i = blockIdx.x * 256 + threadIdx.x;      // over DD*CC
    if (i >= DD * CC) return;
    int d = i / CC, c = i % CC;
    wpt[d * CP + c] = __float2bfloat16(wp[c * DD + d]);
}

// bsum[j] = bih+bhh ; beff[j] = bih+bhh + dot(Wih[j,:], bp)   (fp32)
__global__ void bias_kernel(const float* __restrict__ Wih, const float* __restrict__ bih,
                            const float* __restrict__ bhh, const float* __restrict__ bp,
                            float* __restrict__ bsum, float* __restrict__ beff) {
    int j = blockIdx.x * 256 + threadIdx.x;      // 2048
    if (j >= GG) return;
    float s = bih[j] + bhh[j];
    float acc = 0.f;
    const float* w = Wih + j * CC;
    for (int c = 0; c < CC; ++c) acc += w[c] * bp[c];
    bsum[j] = s;
    beff[j] = s + acc;
}

// ---------------------------------------------------------------------------
// Generic 64x64 block MFMA core: C[m][n] = sum_k A[m][k] * Bt[n][k]
// 256 threads / 4 waves; wave w owns m-tile w (16 rows) x 4 n-tiles.
// K must be a multiple of 32. Verified gfx950 16x16x32 bf16 layouts:
//   A/B frag: lane holds row (lane&15), k = (lane>>4)*8 + 0..7
//   C/D:      col = lane&15 (n), row = (lane>>4)*4 + reg (m)
__device__ __forceinline__ void gemm_core_64x64(const bf16* A, int lda, const bf16* Bt,
                                                int ldb, int K, int m0, int n0,
                                                f32x4 acc[4]) {
    __shared__ unsigned short As[64][40];
    __shared__ unsigned short Bs[64][40];
    int tid = threadIdx.x;
    int w = tid >> 6, lane = tid & 63;
    int quad = lane >> 4, col = lane & 15;
    int lr = tid >> 2, lc = (tid & 3) * 8;
    for (int k0 = 0; k0 < K; k0 += 32) {
        __syncthreads();
        *(uint4*)&As[lr][lc] = *(const uint4*)&A[(size_t)(m0 + lr) * lda + k0 + lc];
        *(uint4*)&Bs[lr][lc] = *(const uint4*)&Bt[(size_t)(n0 + lr) * ldb + k0 + lc];
        __syncthreads();
        bf16x8 a = *(const bf16x8*)&As[w * 16 + col][quad * 8];
#pragma unroll
        for (int nt = 0; nt < 4; ++nt) {
            bf16x8 bfr = *(const bf16x8*)&Bs[nt * 16 + col][quad * 8];
            acc[nt] = __builtin_amdgcn_mfma_f32_16x16x32_bf16(a, bfr, acc[nt], 0, 0, 0);
        }
    }
}

// Weff[j][d] = Whh[j][d] + sum_c Wih[j][c]*Wp[c][d]   (bf16 out)
__global__ void weff_kernel(const bf16* __restrict__ WihP, const bf16* __restrict__ WpTP,
                            const float* __restrict__ Whh, bf16* __restrict__ WeffP) {
    f32x4 acc[4] = {{0,0,0,0},{0,0,0,0},{0,0,0,0},{0,0,0,0}};
    int m0 = blockIdx.y * 64, n0 = blockIdx.x * 64;
    gemm_core_64x64(WihP, CP, WpTP, CP, CP, m0, n0, acc);
    int tid = threadIdx.x, w = tid >> 6, lane = tid & 63;
    int quad = lane >> 4, col = lane & 15;
#pragma unroll
    for (int nt = 0; nt < 4; ++nt)
#pragma unroll
        for (int r = 0; r < 4; ++r) {
            int j = m0 + w * 16 + quad * 4 + r;
            int d = n0 + nt * 16 + col;
            WeffP[j * DD + d] = __float2bfloat16(acc[nt][r] + Whh[j * DD + d]);
        }
}

// Final projection + denorm: out[b][t][c] = (Hdec[t*BB+b,:]@Wp[c,:] + bp[c])*std + mean
__global__ void proj_kernel(const bf16* __restrict__ Hdec, const bf16* __restrict__ WpP,
                            const float* __restrict__ bp, const float* __restrict__ stdp,
                            const float* __restrict__ meanp, float* __restrict__ out) {
    f32x4 acc[4] = {{0,0,0,0},{0,0,0,0},{0,0,0,0},{0,0,0,0}};
    int m0 = blockIdx.x * 64, n0 = blockIdx.y * 64;
    gemm_core_64x64(Hdec, DD, WpP, DD, DD, m0, n0, acc);
    int tid = threadIdx.x, w = tid >> 6, lane = tid & 63;
    int quad = lane >> 4, col = lane & 15;
#pragma unroll
    for (int nt = 0; nt < 4; ++nt) {
        int c = n0 + nt * 16 + col;
        if (c >= CC) continue;
        float bpc = bp[c];
#pragma unroll
        for (int r = 0; r < 4; ++r) {
            int row = m0 + w * 16 + quad * 4 + r;   // = t*BB + b
            int t = row >> 8, b = row & 255;
            float y = acc[nt][r] + bpc;
            int sc = b * CC + c;
            out[(b * PP + t) * CC + c] = y * stdp[sc] + meanp[sc];
        }
    }
}

// ---------------------------------------------------------------------------
// One LSTM step. g[b][j] = (phase0: xt@Wih^T) + h@Wh^T + bias; gate-fused.
// Block: 128 thr (2 waves), tile 32b x (16d x 4 gates). grid (32 d-tiles, 8 b-tiles).
// Gate g's n-tile reads W rows j = g*512 + d0 + (lane&15)  ->  each lane ends up
// holding all 4 gates of its (b,d): epilogue needs no cross-lane traffic.
__global__ __launch_bounds__(128) void lstm_step_kernel(
        const bf16* __restrict__ Ax, int Kx, const bf16* __restrict__ Wx,
        const bf16* __restrict__ h_in, const bf16* __restrict__ Wh,
        const float* __restrict__ bias, float* __restrict__ cst,
        bf16* __restrict__ h_out, bf16* __restrict__ hdec) {
    __shared__ unsigned short As[32][40];
    __shared__ unsigned short Ws[64][40];
    int tid = threadIdx.x;
    int w = tid >> 6;                 // m-tile (0..1)
    int lane = tid & 63;
    int quad = lane >> 4, col = lane & 15;
    int d0 = blockIdx.x * 16;
    int b0 = blockIdx.y * 32;
    f32x4 acc[4] = {{0,0,0,0},{0,0,0,0},{0,0,0,0},{0,0,0,0}};

    int alr = tid >> 2, alc = (tid & 3) * 8;   // A loader: 32 rows x 4x8 shorts
    int wr = tid >> 1, wc = (tid & 1) * 16;    // W loader: 64 rows x 2x16 shorts
    int jrow = (wr >> 4) * DD + d0 + (wr & 15);

#pragma unroll 1
    for (int phase = 0; phase < 2; ++phase) {
        const bf16* Ap; const bf16* Wp_; int ld, K;
        if (phase == 0) { Ap = Ax; Wp_ = Wx; ld = CP; K = Kx; }
        else           { Ap = h_in; Wp_ = Wh; ld = DD; K = DD; }
        for (int k0 = 0; k0 < K; k0 += 32) {
            __syncthreads();
            *(uint4*)&As[alr][alc] = *(const uint4*)&Ap[(size_t)(b0 + alr) * ld + k0 + alc];
            const bf16* wsrc = Wp_ + (size_t)jrow * ld + k0 + wc;
            *(uint4*)&Ws[wr][wc]     = *(const uint4*)wsrc;
            *(uint4*)&Ws[wr][wc + 8] = *(const uint4*)(wsrc + 8);
            __syncthreads();
            bf16x8 a = *(const bf16x8*)&As[w * 16 + col][quad * 8];
#pragma unroll
            for (int g = 0; g < 4; ++g) {
                bf16x8 bb = *(const bf16x8*)&Ws[g * 16 + col][quad * 8];
                acc[g] = __builtin_amdgcn_mfma_f32_16x16x32_bf16(a, bb, acc[g], 0, 0, 0);
            }
        }
    }

    // epilogue: PyTorch gate order [i, f, g, o]
    int d = d0 + col;
    float bi = bias[d], bf_ = bias[DD + d], bg = bias[2 * DD + d], bo = bias[3 * DD + d];
#pragma unroll
    for (int r = 0; r < 4; ++r) {
        int b = b0 + w * 16 + quad * 4 + r;
        float iv = acc[0][r] + bi;
        float fv = acc[1][r] + bf_;
        float gv = acc[2][r] + bg;
        float ov = acc[3][r] + bo;
        float si = 1.f / (1.f + __expf(-iv));
        float sf = 1.f / (1.f + __expf(-fv));
        float so = 1.f / (1.f + __expf(-ov));
        float tg = tanhf(gv);
        size_t idx = (size_t)b * DD + d;
        float cc = sf * cst[idx] + si * tg;
        cst[idx] = cc;
        float hv = so * tanhf(cc);
        bf16 hb = __float2bfloat16(hv);
        h_out[idx] = hb;
        if (hdec) hdec[idx] = hb;
    }
}

// ---------------------------------------------------------------------------
extern "C" void kernel_launch(void* const* d_in, const int* in_sizes, int n_in,
                              void* d_out, int out_size, void* d_ws, size_t ws_size,
                              hipStream_t stream) {
    (void)in_sizes; (void)n_in; (void)out_size;
    const float* x_enc = (const float*)d_in[0];
    const float* Wih   = (const float*)d_in[1];
    const float* Whh   = (const float*)d_in[2];
    const float* bih   = (const float*)d_in[3];
    const float* bhh   = (const float*)d_in[4];
    const float* Wp    = (const float*)d_in[5];
    const float* bp    = (const float*)d_in[6];
    float* out = (float*)d_out;

    // workspace layout (bytes, all 256-aligned)
    char* ws = (char*)d_ws;
    size_t off = 0;
    float* meanp = (float*)(ws + off); off += (size_t)BB * CC * 4;          // 328704
    float* stdp  = (float*)(ws + off); off += (size_t)BB * CC * 4;
    bf16* xnormP = (bf16*)(ws + off);  off += (size_t)TT * BB * CP * 2;     // 17.3MB
    bf16* WihP   = (bf16*)(ws + off);  off += (size_t)GG * CP * 2;
    bf16* WhhP   = (bf16*)(ws + off);  off += (size_t)GG * DD * 2;
    bf16* WeffP  = (bf16*)(ws + off);  off += (size_t)GG * DD * 2;
    bf16* WpTP   = (bf16*)(ws + off);  off += (size_t)DD * CP * 2;
    bf16* WpP    = (bf16*)(ws + off);  off += (size_t)384 * DD * 2;
    float* bsum  = (float*)(ws + off); off += (size_t)GG * 4;
    float* beff  = (float*)(ws + off); off += (size_t)GG * 4;
    bf16* hA     = (bf16*)(ws + off);  off += (size_t)BB * DD * 2;
    bf16* hB     = (bf16*)(ws + off);  off += (size_t)BB * DD * 2;
    float* cst   = (float*)(ws + off); off += (size_t)BB * DD * 4;
    bf16* Hdec   = (bf16*)(ws + off);  off += (size_t)PP * BB * DD * 2;     // 25.2MB
    if (ws_size < off) return;  // ~48.3 MB needed

    // zero-init padded / accumulated regions (ws is poisoned each call)
    hipMemsetAsync(xnormP, 0, (size_t)TT * BB * CP * 2, stream);
    hipMemsetAsync(WihP,   0, (size_t)GG * CP * 2, stream);
    hipMemsetAsync(WpTP,   0, (size_t)DD * CP * 2, stream);
    hipMemsetAsync(WpP,    0, (size_t)384 * DD * 2, stream);
    hipMemsetAsync(hA,     0, (size_t)BB * DD * 2, stream);
    hipMemsetAsync(cst,    0, (size_t)BB * DD * 4, stream);

    norm_kernel<<<(BB * CC + 255) / 256, 256, 0, stream>>>(x_enc, meanp, stdp, xnormP);
    cast_pad_kernel<<<(GG * CC + 255) / 256, 256, 0, stream>>>(Wih, WihP, GG, CC, CP);
    cast_pad_kernel<<<(GG * DD + 255) / 256, 256, 0, stream>>>(Whh, WhhP, GG, DD, DD);
    cast_pad_kernel<<<(CC * DD + 255) / 256, 256, 0, stream>>>(Wp, WpP, CC, DD, DD);
    transpose_wp_kernel<<<(DD * CC + 255) / 256, 256, 0, stream>>>(Wp, WpTP);
    bias_kernel<<<GG / 256, 256, 0, stream>>>(Wih, bih, bhh, bp, bsum, beff);
    weff_kernel<<<dim3(DD / 64, GG / 64), 256, 0, stream>>>(WihP, WpTP, Whh, WeffP);

    bf16* h_cur = hA;
    bf16* h_nxt = hB;
    // encoder: 96 steps, g = xt@Wih^T + h@Whh^T + bsum
    for (int t = 0; t < TT; ++t) {
        bf16* hd = (t == TT - 1) ? Hdec : nullptr;   // Hdec[0] = final encoder h
        lstm_step_kernel<<<dim3(DD / 16, BB / 32), 128, 0, stream>>>(
            xnormP + (size_t)t * BB * CP, CP, WihP, h_cur, WhhP, bsum, cst, h_nxt, hd);
        bf16* tmp = h_cur; h_cur = h_nxt; h_nxt = tmp;
    }
    // decoder: 96 steps, g = h@Weff^T + beff (y folded in); Hdec[t+1] = h_out
    for (int t = 0; t < PP; ++t) {
        bf16* hd = (t < PP - 1) ? Hdec + (size_t)(t + 1) * BB * DD : nullptr;
        lstm_step_kernel<<<dim3(DD / 16, BB / 32), 128, 0, stream>>>(
            nullptr, 0, WihP, h_cur, WeffP, beff, cst, h_nxt, hd);
        bf16* tmp = h_cur; h_cur = h_nxt; h_nxt = tmp;
    }

    // ys = Hdec @ Wp^T + bp, denormalize, write output
    proj_kernel<<<dim3(PP * BB / 64, 384 / 64), 256, 0, stream>>>(
        Hdec, WpP, bp, stdp, meanp, out);
}